// Round 1
// baseline (91.368 us; speedup 1.0000x reference)
//
#include <hip/hip_runtime.h>

// Problem constants (match reference setup_inputs: BS=8, N_OBJ=16, C,H,W=256,7,7, ISEX=True)
constexpr int BS           = 8;
constexpr int N            = 16;
constexpr int CHW          = 256 * 7 * 7;          // 12544 floats per row
constexpr int CHW4         = CHW / 4;              // 3136 float4 per row
constexpr int PAIRS        = N * (N - 1) / 2;      // 120
constexpr int P_PER_IMG    = 2 * PAIRS;            // 240 (isex doubles, interleaved)
constexpr int ROWS_PER_IMG = (N * N + N) / 2;      // 136 (16 obj rows + 120 union rows)
constexpr int P_TOTAL      = BS * P_PER_IMG;       // 1920
constexpr int OUT_ROWS     = P_TOTAL * 3;          // 5760

__global__ __launch_bounds__(256) void obj_pair_gather(
    const float* __restrict__ src, float* __restrict__ dst)
{
    const int row = blockIdx.x;          // 0 .. OUT_ROWS-1  (row = p*3 + j)
    const int p   = row / 3;
    const int j   = row - p * 3;

    const int b   = p / P_PER_IMG;       // image index
    const int k2  = p - b * P_PER_IMG;   // 0 .. 239 within image
    const int k   = k2 >> 1;             // base pair index 0..119
    const int sw  = k2 & 1;              // 0: (o1,o2), 1: (o2,o1)  (isex interleave)

    // Decode row-major triu pair k -> (o1, o2), o1 < o2.  Wave-uniform loop.
    int o1 = 0, rem = k;
    while (rem >= N - 1 - o1) { rem -= N - 1 - o1; ++o1; }
    const int o2 = o1 + 1 + rem;

    const int begin = b * ROWS_PER_IMG;
    int srcRow;
    if (j == 2) {
        srcRow = begin + N + k;                      // union row
    } else {
        const int first  = sw ? o2 : o1;
        const int second = sw ? o1 : o2;
        srcRow = begin + (j == 0 ? first : second);
    }

    const float4* __restrict__ s =
        reinterpret_cast<const float4*>(src + (size_t)srcRow * CHW);
    float4* __restrict__ d =
        reinterpret_cast<float4*>(dst + (size_t)row * CHW);

    for (int i = threadIdx.x; i < CHW4; i += blockDim.x) {
        d[i] = s[i];
    }
}

extern "C" void kernel_launch(void* const* d_in, const int* in_sizes, int n_in,
                              void* d_out, int out_size, void* d_ws, size_t ws_size,
                              hipStream_t stream) {
    const float* roi = (const float*)d_in[0];
    float* out = (float*)d_out;
    obj_pair_gather<<<OUT_ROWS, 256, 0, stream>>>(roi, out);
}

// Round 2
// 68.175 us; speedup vs baseline: 1.3402x; 1.3402x over previous
//
#include <hip/hip_runtime.h>

// Problem constants (match reference setup_inputs: BS=8, N_OBJ=16, C,H,W=256,7,7, ISEX=True)
constexpr int BS           = 8;
constexpr int N            = 16;
constexpr int CHW          = 256 * 7 * 7;          // 12544 floats per row
constexpr int CHW4         = CHW / 4;              // 3136 float4 per row
constexpr int PAIRS        = N * (N - 1) / 2;      // 120
constexpr int P_PER_IMG    = 2 * PAIRS;            // 240 (isex doubles, interleaved)
constexpr int ROWS_PER_IMG = (N * N + N) / 2;      // 136 (16 obj rows + 120 union rows)
constexpr int P_TOTAL      = BS * P_PER_IMG;       // 1920
constexpr int OUT_ROWS     = P_TOTAL * 3;          // 5760

typedef float v4f __attribute__((ext_vector_type(4)));

__global__ __launch_bounds__(256) void obj_pair_gather(
    const float* __restrict__ src, float* __restrict__ dst)
{
    const int row = blockIdx.x;          // 0 .. OUT_ROWS-1  (row = p*3 + j)
    const int p   = row / 3;
    const int j   = row - p * 3;

    const int b   = p / P_PER_IMG;       // image index
    const int k2  = p - b * P_PER_IMG;   // 0 .. 239 within image
    const int k   = k2 >> 1;             // base pair index 0..119
    const int sw  = k2 & 1;              // 0: (o1,o2), 1: (o2,o1)  (isex interleave)

    // Decode row-major triu pair k -> (o1, o2), o1 < o2.  Wave-uniform loop.
    int o1 = 0, rem = k;
    while (rem >= N - 1 - o1) { rem -= N - 1 - o1; ++o1; }
    const int o2 = o1 + 1 + rem;

    const int begin = b * ROWS_PER_IMG;
    int srcRow;
    if (j == 2) {
        srcRow = begin + N + k;                      // union row
    } else {
        const int first  = sw ? o2 : o1;
        const int second = sw ? o1 : o2;
        srcRow = begin + (j == 0 ? first : second);
    }

    const v4f* __restrict__ s =
        reinterpret_cast<const v4f*>(src + (size_t)srcRow * CHW);
    v4f* __restrict__ d =
        reinterpret_cast<v4f*>(dst + (size_t)row * CHW);

    // Streaming (nontemporal) stores: keep the 289 MB write stream from
    // evicting the 55 MB input out of L3, so gather reads stay cache-hits.
    for (int i = threadIdx.x; i < CHW4; i += 256) {
        v4f v = s[i];
        __builtin_nontemporal_store(v, d + i);
    }
}

extern "C" void kernel_launch(void* const* d_in, const int* in_sizes, int n_in,
                              void* d_out, int out_size, void* d_ws, size_t ws_size,
                              hipStream_t stream) {
    const float* roi = (const float*)d_in[0];
    float* out = (float*)d_out;
    obj_pair_gather<<<OUT_ROWS, 256, 0, stream>>>(roi, out);
}

// Round 3
// 57.889 us; speedup vs baseline: 1.5783x; 1.1777x over previous
//
#include <hip/hip_runtime.h>

// Problem constants (match reference setup_inputs: BS=8, N_OBJ=16, C,H,W=256,7,7, ISEX=True)
constexpr int BS           = 8;
constexpr int N            = 16;
constexpr int CHW          = 256 * 7 * 7;          // 12544 floats per row
constexpr int CHW4         = CHW / 4;              // 3136 float4 per row
constexpr int PAIRS        = N * (N - 1) / 2;      // 120
constexpr int P_PER_IMG    = 2 * PAIRS;            // 240 (isex doubles, interleaved)
constexpr int ROWS_PER_IMG = (N * N + N) / 2;      // 136 (16 obj rows + 120 union rows)
constexpr int P_TOTAL      = BS * P_PER_IMG;       // 1920
constexpr int OUT_ROWS     = P_TOTAL * 3;          // 5760
constexpr int ROWS_OUT_PER_IMG = OUT_ROWS / BS;    // 720

typedef float v4f __attribute__((ext_vector_type(4)));

__global__ __launch_bounds__(256) void obj_pair_gather(
    const float* __restrict__ src, float* __restrict__ dst)
{
    // XCD-affinity swizzle: hardware round-robins consecutive block ids
    // across the 8 XCDs (block i -> XCD i%8).  Remap so XCD x processes
    // exactly image x's 720 output rows in temporal pair order: its 16
    // object rows (800 KB) stay resident in that XCD's 4 MiB L2, and each
    // union row's 2nd read (isex twin, adjacent slot) is an L2 hit.
    const int bid  = blockIdx.x;
    const int b    = bid & 7;            // image == XCD
    const int slot = bid >> 3;           // 0 .. 719, temporal order within image
    const int row  = b * ROWS_OUT_PER_IMG + slot;   // output row (= p*3 + j)

    const int p   = row / 3;
    const int j   = row - p * 3;

    const int k2  = slot / 3 == p - b * P_PER_IMG ? p - b * P_PER_IMG : p - b * P_PER_IMG; // (identical; keep simple)
    const int k   = k2 >> 1;             // base pair index 0..119
    const int sw  = k2 & 1;              // 0: (o1,o2), 1: (o2,o1)  (isex interleave)

    // Decode row-major triu pair k -> (o1, o2), o1 < o2.  Wave-uniform loop.
    int o1 = 0, rem = k;
    while (rem >= N - 1 - o1) { rem -= N - 1 - o1; ++o1; }
    const int o2 = o1 + 1 + rem;

    const int begin = b * ROWS_PER_IMG;
    int srcRow;
    if (j == 2) {
        srcRow = begin + N + k;                      // union row
    } else {
        const int first  = sw ? o2 : o1;
        const int second = sw ? o1 : o2;
        srcRow = begin + (j == 0 ? first : second);
    }

    const v4f* __restrict__ s =
        reinterpret_cast<const v4f*>(src + (size_t)srcRow * CHW);
    v4f* __restrict__ d =
        reinterpret_cast<v4f*>(dst + (size_t)row * CHW);

    // Streaming (nontemporal) stores keep the 289 MB write stream from
    // evicting the input; reads then come from L2/L3.
    for (int i = threadIdx.x; i < CHW4; i += 256) {
        v4f v = s[i];
        __builtin_nontemporal_store(v, d + i);
    }
}

extern "C" void kernel_launch(void* const* d_in, const int* in_sizes, int n_in,
                              void* d_out, int out_size, void* d_ws, size_t ws_size,
                              hipStream_t stream) {
    const float* roi = (const float*)d_in[0];
    float* out = (float*)d_out;
    obj_pair_gather<<<OUT_ROWS, 256, 0, stream>>>(roi, out);
}

// Round 4
// 55.595 us; speedup vs baseline: 1.6434x; 1.0413x over previous
//
#include <hip/hip_runtime.h>

// Problem constants (match reference setup_inputs: BS=8, N_OBJ=16, C,H,W=256,7,7, ISEX=True)
constexpr int BS           = 8;
constexpr int N            = 16;
constexpr int CHW          = 256 * 7 * 7;          // 12544 floats per row
constexpr int CHW4         = CHW / 4;              // 3136 float4 per row
constexpr int PAIRS        = N * (N - 1) / 2;      // 120
constexpr int P_PER_IMG    = 2 * PAIRS;            // 240 (isex doubles, interleaved)
constexpr int ROWS_PER_IMG = (N * N + N) / 2;      // 136 (16 obj rows + 120 union rows)
constexpr int P_TOTAL      = BS * P_PER_IMG;       // 1920
constexpr int OUT_ROWS     = P_TOTAL * 3;          // 5760
constexpr int ROWS_OUT_PER_IMG = OUT_ROWS / BS;    // 720
constexpr int ITERS        = (CHW4 + 255) / 256;   // 13 (last iter: lanes 0..63 only)

typedef float v4f __attribute__((ext_vector_type(4)));

__global__ __launch_bounds__(256) void obj_pair_gather(
    const float* __restrict__ src, float* __restrict__ dst)
{
    // XCD-affinity swizzle: hardware round-robins consecutive block ids
    // across the 8 XCDs (block i -> XCD i%8).  XCD x processes image x's
    // 720 output rows in temporal order: its 16 object rows (800 KB) stay
    // L2-resident, and each union row's isex-twin read is an L2 hit.
    const int bid  = blockIdx.x;
    const int b    = bid & 7;            // image == XCD
    const int slot = bid >> 3;           // 0 .. 719, temporal order within image
    const int row  = b * ROWS_OUT_PER_IMG + slot;   // output row (= p*3 + j)

    const int p   = row / 3;
    const int j   = row - p * 3;

    const int k2  = p - b * P_PER_IMG;   // 0 .. 239 within image
    const int k   = k2 >> 1;             // base pair index 0..119
    const int sw  = k2 & 1;              // 0: (o1,o2), 1: (o2,o1)  (isex interleave)

    // Decode row-major triu pair k -> (o1, o2), o1 < o2.  Wave-uniform loop.
    int o1 = 0, rem = k;
    while (rem >= N - 1 - o1) { rem -= N - 1 - o1; ++o1; }
    const int o2 = o1 + 1 + rem;

    const int begin = b * ROWS_PER_IMG;
    int srcRow;
    if (j == 2) {
        srcRow = begin + N + k;                      // union row
    } else {
        const int first  = sw ? o2 : o1;
        const int second = sw ? o1 : o2;
        srcRow = begin + (j == 0 ? first : second);
    }

    const v4f* __restrict__ s =
        reinterpret_cast<const v4f*>(src + (size_t)srcRow * CHW);
    v4f* __restrict__ d =
        reinterpret_cast<v4f*>(dst + (size_t)row * CHW);

    // Stage the whole 49 KB row in registers (13 independent dwordx4 loads
    // per thread -> deep MLP, L2-hit latency pipelined), THEN issue all
    // nt-stores: long same-direction bursts instead of fine read<->write
    // interleave, minimizing HBM bus turnaround.
    v4f r[ITERS];
    #pragma unroll
    for (int it = 0; it < ITERS; ++it) {
        const int i = (int)threadIdx.x + it * 256;
        if (it < ITERS - 1 || i < CHW4) r[it] = s[i];
    }
    #pragma unroll
    for (int it = 0; it < ITERS; ++it) {
        const int i = (int)threadIdx.x + it * 256;
        if (it < ITERS - 1 || i < CHW4) __builtin_nontemporal_store(r[it], d + i);
    }
}

extern "C" void kernel_launch(void* const* d_in, const int* in_sizes, int n_in,
                              void* d_out, int out_size, void* d_ws, size_t ws_size,
                              hipStream_t stream) {
    const float* roi = (const float*)d_in[0];
    float* out = (float*)d_out;
    obj_pair_gather<<<OUT_ROWS, 256, 0, stream>>>(roi, out);
}